// Round 8
// baseline (145.003 us; speedup 1.0000x reference)
//
#include <hip/hip_runtime.h>

#define NSEG 6
#define NBLOCKS 2048
#define NTHREADS 256

typedef int vint4 __attribute__((ext_vector_type(4)));

__device__ __forceinline__ void consume4(const float4 p, const vint4 t, const vint4 w,
                                         float (&ps)[NSEG], float (&cn)[NSEG]) {
    int s0 = t.x * 3 + w.x;
    int s1 = t.y * 3 + w.y;
    int s2 = t.z * 3 + w.z;
    int s3 = t.w * 3 + w.w;
#pragma unroll
    for (int s = 0; s < NSEG; ++s) {
        if (s0 == s) { ps[s] += p.x; cn[s] += 1.f; }
        if (s1 == s) { ps[s] += p.y; cn[s] += 1.f; }
        if (s2 == s) { ps[s] += p.z; cn[s] += 1.f; }
        if (s3 == s) { ps[s] += p.w; cn[s] += 1.f; }
    }
}

__global__ __launch_bounds__(NTHREADS) void wdice_partial(
    const float4* __restrict__ pred,
    const vint4* __restrict__ tgt,
    const vint4* __restrict__ wt,
    int nvec,
    float* __restrict__ psum_out,   // [NBLOCKS*NSEG]
    float* __restrict__ cnt_out)    // [NBLOCKS*NSEG]
{
    float ps[NSEG];
    float cn[NSEG];
#pragma unroll
    for (int s = 0; s < NSEG; ++s) { ps[s] = 0.f; cn[s] = 0.f; }

    int tid = blockIdx.x * blockDim.x + threadIdx.x;
    int stride = gridDim.x * blockDim.x;

    int i = tid;
    // unroll x2: pred via normal (cacheable, L3-resident) loads; int streams via
    // sc0|sc1|nt loads = scope-escalated, no cache allocation -> don't evict pred from L3.
    for (; i + stride < nvec; i += 2 * stride) {
        float4 p0 = pred[i];
        float4 p1 = pred[i + stride];
        vint4 t0, w0, t1, w1;
        asm volatile(
            "global_load_dwordx4 %0, %4, off sc0 sc1 nt\n\t"
            "global_load_dwordx4 %1, %5, off sc0 sc1 nt\n\t"
            "global_load_dwordx4 %2, %6, off sc0 sc1 nt\n\t"
            "global_load_dwordx4 %3, %7, off sc0 sc1 nt\n\t"
            "s_waitcnt vmcnt(0)"
            : "=&v"(t0), "=&v"(w0), "=&v"(t1), "=&v"(w1)
            : "v"(&tgt[i]), "v"(&wt[i]), "v"(&tgt[i + stride]), "v"(&wt[i + stride])
            : "memory");
        consume4(p0, t0, w0, ps, cn);
        consume4(p1, t1, w1, ps, cn);
    }
    // tail
    for (; i < nvec; i += stride) {
        float4 p = pred[i];
        vint4 t = __builtin_nontemporal_load(&tgt[i]);
        vint4 w = __builtin_nontemporal_load(&wt[i]);
        consume4(p, t, w, ps, cn);
    }

    // wave (64-lane) shuffle reduction
#pragma unroll
    for (int s = 0; s < NSEG; ++s) {
#pragma unroll
        for (int off = 32; off > 0; off >>= 1) {
            ps[s] += __shfl_down(ps[s], off, 64);
            cn[s] += __shfl_down(cn[s], off, 64);
        }
    }

    __shared__ float lps[4][NSEG];
    __shared__ float lcn[4][NSEG];
    int lane = threadIdx.x & 63;
    int wave = threadIdx.x >> 6;
    if (lane == 0) {
#pragma unroll
        for (int s = 0; s < NSEG; ++s) { lps[wave][s] = ps[s]; lcn[wave][s] = cn[s]; }
    }
    __syncthreads();
    if (threadIdx.x == 0) {
#pragma unroll
        for (int s = 0; s < NSEG; ++s) {
            float tps = lps[0][s] + lps[1][s] + lps[2][s] + lps[3][s];
            float tcn = lcn[0][s] + lcn[1][s] + lcn[2][s] + lcn[3][s];
            psum_out[blockIdx.x * NSEG + s] = tps;
            cnt_out[blockIdx.x * NSEG + s] = tcn;
        }
    }
}

__global__ __launch_bounds__(NTHREADS) void wdice_final(
    const float* __restrict__ psum_in,
    const float* __restrict__ cnt_in,
    int nrows,
    float* __restrict__ out)
{
    double ps[NSEG];
    double cn[NSEG];
#pragma unroll
    for (int s = 0; s < NSEG; ++s) { ps[s] = 0.0; cn[s] = 0.0; }

    for (int r = threadIdx.x; r < nrows; r += blockDim.x) {
#pragma unroll
        for (int s = 0; s < NSEG; ++s) {
            ps[s] += (double)psum_in[r * NSEG + s];
            cn[s] += (double)cnt_in[r * NSEG + s];
        }
    }

#pragma unroll
    for (int s = 0; s < NSEG; ++s) {
#pragma unroll
        for (int off = 32; off > 0; off >>= 1) {
            ps[s] += __shfl_down(ps[s], off, 64);
            cn[s] += __shfl_down(cn[s], off, 64);
        }
    }

    __shared__ double lps[4][NSEG];
    __shared__ double lcn[4][NSEG];
    int lane = threadIdx.x & 63;
    int wave = threadIdx.x >> 6;
    if (lane == 0) {
#pragma unroll
        for (int s = 0; s < NSEG; ++s) { lps[wave][s] = ps[s]; lcn[wave][s] = cn[s]; }
    }
    __syncthreads();
    if (threadIdx.x == 0) {
        double numer = 0.0, denom = 0.0;
#pragma unroll
        for (int s = 0; s < NSEG; ++s) {
            double tps = lps[0][s] + lps[1][s] + lps[2][s] + lps[3][s];
            double tcn = lcn[0][s] + lcn[1][s] + lcn[2][s] + lcn[3][s];
            if (tcn > 0.0) {
                double inv_n2 = 1.0 / (tcn * tcn);
                numer += tps * inv_n2;
                denom += (tps + tcn) * inv_n2;
            }
        }
        out[0] = (float)(1.0 - 2.0 * numer / denom);
    }
}

extern "C" void kernel_launch(void* const* d_in, const int* in_sizes, int n_in,
                              void* d_out, int out_size, void* d_ws, size_t ws_size,
                              hipStream_t stream) {
    const float4* pred = (const float4*)d_in[0];
    const vint4* tgt = (const vint4*)d_in[1];
    const vint4* wt = (const vint4*)d_in[2];
    int n = in_sizes[0];
    int nvec = n / 4;

    float* psum_ws = (float*)d_ws;
    float* cnt_ws = psum_ws + NBLOCKS * NSEG;

    wdice_partial<<<NBLOCKS, NTHREADS, 0, stream>>>(pred, tgt, wt, nvec, psum_ws, cnt_ws);
    wdice_final<<<1, NTHREADS, 0, stream>>>(psum_ws, cnt_ws, NBLOCKS, (float*)d_out);
}

// Round 9
// 134.167 us; speedup vs baseline: 1.0808x; 1.0808x over previous
//
#include <hip/hip_runtime.h>

#define NSEG 6
#define NBLOCKS 2048
#define NTHREADS 256

typedef int vint4 __attribute__((ext_vector_type(4)));
typedef float vfloat4 __attribute__((ext_vector_type(4)));

__global__ __launch_bounds__(NTHREADS) void wdice_partial(
    const vfloat4* __restrict__ pred,
    const vint4* __restrict__ tgt,
    const vint4* __restrict__ wt,
    int nvec,
    float* __restrict__ psum_out,   // [NBLOCKS*NSEG]
    float* __restrict__ cnt_out)    // [NBLOCKS*NSEG]
{
    float ps[NSEG];
    float cn[NSEG];
#pragma unroll
    for (int s = 0; s < NSEG; ++s) { ps[s] = 0.f; cn[s] = 0.f; }

    int tid = blockIdx.x * blockDim.x + threadIdx.x;
    int stride = gridDim.x * blockDim.x;
    for (int i = tid; i < nvec; i += stride) {
        vfloat4 p = __builtin_nontemporal_load(&pred[i]);  // nt: skip cache allocation (pure stream)
        vint4 t = __builtin_nontemporal_load(&tgt[i]);     // nt
        vint4 w = __builtin_nontemporal_load(&wt[i]);      // nt
        int seg0 = t.x * 3 + w.x;
        int seg1 = t.y * 3 + w.y;
        int seg2 = t.z * 3 + w.z;
        int seg3 = t.w * 3 + w.w;
#pragma unroll
        for (int s = 0; s < NSEG; ++s) {
            if (seg0 == s) { ps[s] += p.x; cn[s] += 1.f; }
            if (seg1 == s) { ps[s] += p.y; cn[s] += 1.f; }
            if (seg2 == s) { ps[s] += p.z; cn[s] += 1.f; }
            if (seg3 == s) { ps[s] += p.w; cn[s] += 1.f; }
        }
    }

    // wave (64-lane) shuffle reduction
#pragma unroll
    for (int s = 0; s < NSEG; ++s) {
#pragma unroll
        for (int off = 32; off > 0; off >>= 1) {
            ps[s] += __shfl_down(ps[s], off, 64);
            cn[s] += __shfl_down(cn[s], off, 64);
        }
    }

    __shared__ float lps[4][NSEG];
    __shared__ float lcn[4][NSEG];
    int lane = threadIdx.x & 63;
    int wave = threadIdx.x >> 6;
    if (lane == 0) {
#pragma unroll
        for (int s = 0; s < NSEG; ++s) { lps[wave][s] = ps[s]; lcn[wave][s] = cn[s]; }
    }
    __syncthreads();
    if (threadIdx.x == 0) {
#pragma unroll
        for (int s = 0; s < NSEG; ++s) {
            float tps = lps[0][s] + lps[1][s] + lps[2][s] + lps[3][s];
            float tcn = lcn[0][s] + lcn[1][s] + lcn[2][s] + lcn[3][s];
            psum_out[blockIdx.x * NSEG + s] = tps;
            cnt_out[blockIdx.x * NSEG + s] = tcn;
        }
    }
}

__global__ __launch_bounds__(NTHREADS) void wdice_final(
    const float* __restrict__ psum_in,
    const float* __restrict__ cnt_in,
    int nrows,
    float* __restrict__ out)
{
    double ps[NSEG];
    double cn[NSEG];
#pragma unroll
    for (int s = 0; s < NSEG; ++s) { ps[s] = 0.0; cn[s] = 0.0; }

    for (int r = threadIdx.x; r < nrows; r += blockDim.x) {
#pragma unroll
        for (int s = 0; s < NSEG; ++s) {
            ps[s] += (double)psum_in[r * NSEG + s];
            cn[s] += (double)cnt_in[r * NSEG + s];
        }
    }

#pragma unroll
    for (int s = 0; s < NSEG; ++s) {
#pragma unroll
        for (int off = 32; off > 0; off >>= 1) {
            ps[s] += __shfl_down(ps[s], off, 64);
            cn[s] += __shfl_down(cn[s], off, 64);
        }
    }

    __shared__ double lps[4][NSEG];
    __shared__ double lcn[4][NSEG];
    int lane = threadIdx.x & 63;
    int wave = threadIdx.x >> 6;
    if (lane == 0) {
#pragma unroll
        for (int s = 0; s < NSEG; ++s) { lps[wave][s] = ps[s]; lcn[wave][s] = cn[s]; }
    }
    __syncthreads();
    if (threadIdx.x == 0) {
        double numer = 0.0, denom = 0.0;
#pragma unroll
        for (int s = 0; s < NSEG; ++s) {
            double tps = lps[0][s] + lps[1][s] + lps[2][s] + lps[3][s];
            double tcn = lcn[0][s] + lcn[1][s] + lcn[2][s] + lcn[3][s];
            if (tcn > 0.0) {
                double inv_n2 = 1.0 / (tcn * tcn);
                numer += tps * inv_n2;
                denom += (tps + tcn) * inv_n2;
            }
        }
        out[0] = (float)(1.0 - 2.0 * numer / denom);
    }
}

extern "C" void kernel_launch(void* const* d_in, const int* in_sizes, int n_in,
                              void* d_out, int out_size, void* d_ws, size_t ws_size,
                              hipStream_t stream) {
    const vfloat4* pred = (const vfloat4*)d_in[0];
    const vint4* tgt = (const vint4*)d_in[1];
    const vint4* wt = (const vint4*)d_in[2];
    int n = in_sizes[0];
    int nvec = n / 4;

    float* psum_ws = (float*)d_ws;
    float* cnt_ws = psum_ws + NBLOCKS * NSEG;

    wdice_partial<<<NBLOCKS, NTHREADS, 0, stream>>>(pred, tgt, wt, nvec, psum_ws, cnt_ws);
    wdice_final<<<1, NTHREADS, 0, stream>>>(psum_ws, cnt_ws, NBLOCKS, (float*)d_out);
}

// Round 10
// 133.277 us; speedup vs baseline: 1.0880x; 1.0067x over previous
//
#include <hip/hip_runtime.h>

#define NSEG 6
#define NBLOCKS 2048
#define NTHREADS 256

typedef int vint4 __attribute__((ext_vector_type(4)));

__global__ __launch_bounds__(NTHREADS) void wdice_partial(
    const float4* __restrict__ pred,
    const vint4* __restrict__ tgt,
    const vint4* __restrict__ wt,
    int nvec,
    float* __restrict__ psum_out,   // [NBLOCKS*NSEG]
    float* __restrict__ cnt_out)    // [NBLOCKS*NSEG]
{
    float ps[NSEG];
    float cn[NSEG];
#pragma unroll
    for (int s = 0; s < NSEG; ++s) { ps[s] = 0.f; cn[s] = 0.f; }

    int tid = blockIdx.x * blockDim.x + threadIdx.x;
    int stride = gridDim.x * blockDim.x;
    for (int i = tid; i < nvec; i += stride) {
        float4 p = pred[i];                              // cacheable
        vint4 t = __builtin_nontemporal_load(&tgt[i]);   // nt: skip cache allocation
        vint4 w = __builtin_nontemporal_load(&wt[i]);    // nt
        int seg0 = t.x * 3 + w.x;
        int seg1 = t.y * 3 + w.y;
        int seg2 = t.z * 3 + w.z;
        int seg3 = t.w * 3 + w.w;
#pragma unroll
        for (int s = 0; s < NSEG; ++s) {
            if (seg0 == s) { ps[s] += p.x; cn[s] += 1.f; }
            if (seg1 == s) { ps[s] += p.y; cn[s] += 1.f; }
            if (seg2 == s) { ps[s] += p.z; cn[s] += 1.f; }
            if (seg3 == s) { ps[s] += p.w; cn[s] += 1.f; }
        }
    }

    // wave (64-lane) shuffle reduction
#pragma unroll
    for (int s = 0; s < NSEG; ++s) {
#pragma unroll
        for (int off = 32; off > 0; off >>= 1) {
            ps[s] += __shfl_down(ps[s], off, 64);
            cn[s] += __shfl_down(cn[s], off, 64);
        }
    }

    __shared__ float lps[4][NSEG];
    __shared__ float lcn[4][NSEG];
    int lane = threadIdx.x & 63;
    int wave = threadIdx.x >> 6;
    if (lane == 0) {
#pragma unroll
        for (int s = 0; s < NSEG; ++s) { lps[wave][s] = ps[s]; lcn[wave][s] = cn[s]; }
    }
    __syncthreads();
    if (threadIdx.x == 0) {
#pragma unroll
        for (int s = 0; s < NSEG; ++s) {
            float tps = lps[0][s] + lps[1][s] + lps[2][s] + lps[3][s];
            float tcn = lcn[0][s] + lcn[1][s] + lcn[2][s] + lcn[3][s];
            psum_out[blockIdx.x * NSEG + s] = tps;
            cnt_out[blockIdx.x * NSEG + s] = tcn;
        }
    }
}

__global__ __launch_bounds__(NTHREADS) void wdice_final(
    const float* __restrict__ psum_in,
    const float* __restrict__ cnt_in,
    int nrows,
    float* __restrict__ out)
{
    double ps[NSEG];
    double cn[NSEG];
#pragma unroll
    for (int s = 0; s < NSEG; ++s) { ps[s] = 0.0; cn[s] = 0.0; }

    for (int r = threadIdx.x; r < nrows; r += blockDim.x) {
#pragma unroll
        for (int s = 0; s < NSEG; ++s) {
            ps[s] += (double)psum_in[r * NSEG + s];
            cn[s] += (double)cnt_in[r * NSEG + s];
        }
    }

#pragma unroll
    for (int s = 0; s < NSEG; ++s) {
#pragma unroll
        for (int off = 32; off > 0; off >>= 1) {
            ps[s] += __shfl_down(ps[s], off, 64);
            cn[s] += __shfl_down(cn[s], off, 64);
        }
    }

    __shared__ double lps[4][NSEG];
    __shared__ double lcn[4][NSEG];
    int lane = threadIdx.x & 63;
    int wave = threadIdx.x >> 6;
    if (lane == 0) {
#pragma unroll
        for (int s = 0; s < NSEG; ++s) { lps[wave][s] = ps[s]; lcn[wave][s] = cn[s]; }
    }
    __syncthreads();
    if (threadIdx.x == 0) {
        double numer = 0.0, denom = 0.0;
#pragma unroll
        for (int s = 0; s < NSEG; ++s) {
            double tps = lps[0][s] + lps[1][s] + lps[2][s] + lps[3][s];
            double tcn = lcn[0][s] + lcn[1][s] + lcn[2][s] + lcn[3][s];
            if (tcn > 0.0) {
                double inv_n2 = 1.0 / (tcn * tcn);
                numer += tps * inv_n2;
                denom += (tps + tcn) * inv_n2;
            }
        }
        out[0] = (float)(1.0 - 2.0 * numer / denom);
    }
}

extern "C" void kernel_launch(void* const* d_in, const int* in_sizes, int n_in,
                              void* d_out, int out_size, void* d_ws, size_t ws_size,
                              hipStream_t stream) {
    const float4* pred = (const float4*)d_in[0];
    const vint4* tgt = (const vint4*)d_in[1];
    const vint4* wt = (const vint4*)d_in[2];
    int n = in_sizes[0];
    int nvec = n / 4;

    float* psum_ws = (float*)d_ws;
    float* cnt_ws = psum_ws + NBLOCKS * NSEG;

    wdice_partial<<<NBLOCKS, NTHREADS, 0, stream>>>(pred, tgt, wt, nvec, psum_ws, cnt_ws);
    wdice_final<<<1, NTHREADS, 0, stream>>>(psum_ws, cnt_ws, NBLOCKS, (float*)d_out);
}